// Round 1
// baseline (95.322 us; speedup 1.0000x reference)
//
#include <hip/hip_runtime.h>

#define N_RAYS   65536
#define NS       256
#define NSM1     255
#define EPS_V    1e-5f

__global__ __launch_bounds__(256) void nerf_render_kernel(
    const float* __restrict__ t,
    const float* __restrict__ sdf,
    const float* __restrict__ color,
    const float* __restrict__ s_inv_log,
    float* __restrict__ out)
{
    const int lane = threadIdx.x & 63;
    const int wave = threadIdx.x >> 6;
    const int ray  = blockIdx.x * 4 + wave;

    float* __restrict__ c_out  = out;                               // 65536*3
    float* __restrict__ d_out  = out + (size_t)N_RAYS * 3;          // 65536
    float* __restrict__ wi_out = out + (size_t)N_RAYS * 4;          // 65536*255
    float* __restrict__ t_out  = wi_out + (size_t)N_RAYS * NSM1;    // 65536*255

    const float s = expf(-s_inv_log[0]);

    const size_t base = (size_t)ray * NS + (size_t)lane * 4;

    // Aligned float4 loads (base*4 bytes is a multiple of 16).
    const float4 sd = *reinterpret_cast<const float4*>(sdf + base);
    const float4 tv = *reinterpret_cast<const float4*>(t   + base);

    // color: 12 consecutive floats starting at base*3 (byte offset ray*3072 + lane*48 -> 16B aligned)
    const float4* cp = reinterpret_cast<const float4*>(color + base * 3);
    const float4 c0 = cp[0];
    const float4 c1 = cp[1];
    const float4 c2 = cp[2];
    const float c[12] = { c0.x, c0.y, c0.z, c0.w,
                          c1.x, c1.y, c1.z, c1.w,
                          c2.x, c2.y, c2.z, c2.w };

    // q = sigmoid(sdf * s)
    float q[5];
    q[0] = 1.0f / (1.0f + expf(-sd.x * s));
    q[1] = 1.0f / (1.0f + expf(-sd.y * s));
    q[2] = 1.0f / (1.0f + expf(-sd.z * s));
    q[3] = 1.0f / (1.0f + expf(-sd.w * s));
    q[4] = __shfl_down(q[0], 1, 64);   // next lane's first q (unused on lane 63)

    float alpha[4], m[4];
    #pragma unroll
    for (int k = 0; k < 4; ++k) {
        float a = (q[k] - q[k + 1] + EPS_V) / (q[k] + EPS_V);
        a = fminf(fmaxf(a, 0.0f), 1.0f);
        if (lane == 63 && k == 3) a = 0.0f;   // sample 255 has no alpha
        alpha[k] = a;
        m[k] = 1.0f - a;
    }

    // In-lane exclusive prefix products of m
    float e[4];
    e[0] = 1.0f;
    e[1] = m[0];
    e[2] = e[1] * m[1];
    e[3] = e[2] * m[2];
    const float L = e[3] * m[3];   // local total product

    // Inclusive wave scan (product) of L across 64 lanes
    float p = L;
    #pragma unroll
    for (int off = 1; off < 64; off <<= 1) {
        float v = __shfl_up(p, off, 64);
        if (lane >= off) p *= v;
    }
    // Exclusive: product over lanes < l
    float Ew = __shfl_up(p, 1, 64);
    if (lane == 0) Ew = 1.0f;

    // wi = Ti * alpha, Ti[4l+k] = Ew * e[k]
    float wi[4];
    #pragma unroll
    for (int k = 0; k < 4; ++k) wi[k] = Ew * e[k] * alpha[k];

    // Stream out wi and t[:-1] (contiguous per wave; last lane writes 3)
    const size_t wbase = (size_t)ray * NSM1 + (size_t)lane * 4;
    const float tvk[4] = { tv.x, tv.y, tv.z, tv.w };
    const int nw = (lane == 63) ? 3 : 4;
    #pragma unroll
    for (int k = 0; k < 4; ++k) {
        if (k < nw) {
            wi_out[wbase + k] = wi[k];
            t_out [wbase + k] = tvk[k];
        }
    }

    // Per-lane partial sums
    float dsum = 0.0f, rs = 0.0f, gs = 0.0f, bs = 0.0f;
    #pragma unroll
    for (int k = 0; k < 4; ++k) {
        dsum += wi[k] * tvk[k];
        rs   += wi[k] * c[3 * k + 0];
        gs   += wi[k] * c[3 * k + 1];
        bs   += wi[k] * c[3 * k + 2];
    }

    // Wave reduction (64 lanes)
    #pragma unroll
    for (int off = 32; off > 0; off >>= 1) {
        dsum += __shfl_xor(dsum, off, 64);
        rs   += __shfl_xor(rs,   off, 64);
        gs   += __shfl_xor(gs,   off, 64);
        bs   += __shfl_xor(bs,   off, 64);
    }

    if (lane == 0) {
        c_out[(size_t)ray * 3 + 0] = rs;
        c_out[(size_t)ray * 3 + 1] = gs;
        c_out[(size_t)ray * 3 + 2] = bs;
        d_out[ray] = dsum;
    }
}

extern "C" void kernel_launch(void* const* d_in, const int* in_sizes, int n_in,
                              void* d_out, int out_size, void* d_ws, size_t ws_size,
                              hipStream_t stream) {
    const float* t     = (const float*)d_in[0];
    const float* sdf   = (const float*)d_in[1];
    const float* color = (const float*)d_in[2];
    const float* sil   = (const float*)d_in[3];
    float* out = (float*)d_out;

    const int blocks = N_RAYS / 4;   // 4 rays (waves) per 256-thread block
    nerf_render_kernel<<<blocks, 256, 0, stream>>>(t, sdf, color, sil, out);
}